// Round 9
// baseline (3454.052 us; speedup 1.0000x reference)
//
#include <hip/hip_runtime.h>
#include <math.h>

#define EMBD   64
#define USERS  100000
#define ITEMS  50000
#define NODES  150000
#define NNZ_C  4500000
#define NENT   100000
#define EPER   16
#define NBLK_SCAN 586   // ceil(150000/256)

// ===========================================================================
// Eigen pexp_float replica (Cephes-style; XLA:CPU vector exp):
// clamp, m = floor(x*log2e + 0.5), 2-step Cody-Waite (0.693359375 /
// -2.12194440e-4), degree-5 poly, y = poly*r^2 + r + 1, scale 2^m.
// ===========================================================================
__device__ __forceinline__ float eigen_expf(float x) {
    x = fminf(fmaxf(x, -87.33654785156250f), 88.72283935546875f);
    float m = floorf(__fmaf_rn(x, 1.44269504088896341f, 0.5f));
    float r = __fsub_rn(x, __fmul_rn(m, 0.693359375f));
    r = __fsub_rn(r, __fmul_rn(m, -2.12194440e-4f));
    float z = __fmul_rn(r, r);
    float y = 1.9875691500e-4f;
    y = __fmaf_rn(y, r, 1.3981999507e-3f);
    y = __fmaf_rn(y, r, 8.3334519073e-3f);
    y = __fmaf_rn(y, r, 4.1665795894e-2f);
    y = __fmaf_rn(y, r, 1.6666665459e-1f);
    y = __fmaf_rn(y, r, 5.0000001201e-1f);
    y = __fmaf_rn(y, z, r);
    y = __fadd_rn(y, 1.0f);
    int mi = (int)m;
    return __int_as_float(__float_as_int(y) + (mi << 23));
}

// ===========================================================================
// Eigen ptanh_float replica (rational 13/6, FMA Horner, tiny-path).
// ===========================================================================
__device__ __forceinline__ float eigen_tanhf(float x) {
    float ax = fabsf(x);
    float x2 = __fmul_rn(x, x);
    float p = -2.76076847742355e-16f;
    p = __fmaf_rn(p, x2, 2.00018790482477e-13f);
    p = __fmaf_rn(p, x2, -8.60467152213735e-11f);
    p = __fmaf_rn(p, x2, 5.12229709037114e-08f);
    p = __fmaf_rn(p, x2, 1.48572235717979e-05f);
    p = __fmaf_rn(p, x2, 6.37261928875436e-04f);
    p = __fmaf_rn(p, x2, 4.89352455891786e-03f);
    p = __fmul_rn(x, p);
    float q = 1.19825839466702e-06f;
    q = __fmaf_rn(q, x2, 1.18534705686654e-04f);
    q = __fmaf_rn(q, x2, 2.26843463243900e-03f);
    q = __fmaf_rn(q, x2, 4.89352518554385e-03f);
    float r = __fdiv_rn(p, q);
    return (ax < 4.0e-4f) ? x : r;
}

// ===========================================================================
// LLVM/XLA-style halving reduce for n=64 contiguous:
// lanewise (v0+v1)+(v2+v3) over 16-lane groups, then halving tree 8,4,2,1.
// ===========================================================================
__device__ __forceinline__ float np_sum64(const float* S, int lane) {
    int j = lane & 15;
    float v = __fadd_rn(__fadd_rn(S[j], S[j + 16]),
                        __fadd_rn(S[j + 32], S[j + 48]));
    v = __fadd_rn(v, __shfl_xor(v, 8));
    v = __fadd_rn(v, __shfl_xor(v, 4));
    v = __fadd_rn(v, __shfl_xor(v, 2));
    v = __fadd_rn(v, __shfl_xor(v, 1));
    return v;
}

// ===========================================================================
// CSR build: count -> scan -> stable scatter (atomic + per-row sort by edge id)
// ===========================================================================
__global__ void count_kernel(const int* __restrict__ rows, int* __restrict__ cnt) {
    int i = blockIdx.x * blockDim.x + threadIdx.x;
    int stride = gridDim.x * blockDim.x;
    for (; i < NNZ_C; i += stride) atomicAdd(&cnt[rows[i]], 1);
}

__global__ void scan1_kernel(const int* __restrict__ cnt, int* __restrict__ bsum) {
    __shared__ int s[256];
    int i = blockIdx.x * 256 + threadIdx.x;
    int v = (i < NODES) ? cnt[i] : 0;
    s[threadIdx.x] = v; __syncthreads();
    for (int o = 128; o; o >>= 1) {
        if (threadIdx.x < o) s[threadIdx.x] += s[threadIdx.x + o];
        __syncthreads();
    }
    if (threadIdx.x == 0) bsum[blockIdx.x] = s[0];
}

__global__ void scan2_kernel(int* __restrict__ bsum) {
    if (blockIdx.x == 0 && threadIdx.x == 0) {
        int acc = 0;
        for (int b = 0; b < NBLK_SCAN; ++b) { int t = bsum[b]; bsum[b] = acc; acc += t; }
    }
}

__global__ void scan3_kernel(const int* __restrict__ cnt, const int* __restrict__ bsum,
                             int* __restrict__ rowptr) {
    __shared__ int s[256];
    int tid = threadIdx.x;
    int i = blockIdx.x * 256 + tid;
    int v = (i < NODES) ? cnt[i] : 0;
    s[tid] = v; __syncthreads();
    for (int o = 1; o < 256; o <<= 1) {
        int t = (tid >= o) ? s[tid - o] : 0;
        __syncthreads();
        s[tid] += t;
        __syncthreads();
    }
    if (i < NODES) rowptr[i] = bsum[blockIdx.x] + s[tid] - v;   // exclusive
}

__global__ void scatter_kernel(const int* __restrict__ rows,
                               const int* __restrict__ rowptr,
                               int* __restrict__ cur, int* __restrict__ eord) {
    int i = blockIdx.x * blockDim.x + threadIdx.x;
    int stride = gridDim.x * blockDim.x;
    for (; i < NNZ_C; i += stride) {
        int r = rows[i];
        int slot = rowptr[r] + atomicAdd(&cur[r], 1);
        eord[slot] = i;
    }
}

__global__ void sortrow_kernel(const int* __restrict__ rowptr,
                               const int* __restrict__ cnt,
                               int* __restrict__ eord) {
    int r = blockIdx.x * blockDim.x + threadIdx.x;
    if (r >= NODES) return;
    int s = rowptr[r], n = cnt[r];
    for (int i = 1; i < n; ++i) {
        int key = eord[s + i];
        int j = i - 1;
        while (j >= 0 && eord[s + j] > key) { eord[s + j + 1] = eord[s + j]; --j; }
        eord[s + j + 1] = key;
    }
}

// ===========================================================================
// SpMM: one wave per row, sequential f32 edge-order accumulation, NO FMA
// ===========================================================================
__global__ void spmm_seq_kernel(const int*   __restrict__ rowptr,
                                const int*   __restrict__ cnt,
                                const int*   __restrict__ eord,
                                const int*   __restrict__ cols,
                                const float* __restrict__ vals,
                                const float* __restrict__ x,
                                float*       __restrict__ y) {
    int lane = threadIdx.x & 63;
    int r = (blockIdx.x * blockDim.x + threadIdx.x) >> 6;
    if (r >= NODES) return;
    int s = rowptr[r], n = cnt[r];
    float acc = 0.f;
    for (int i = 0; i < n; ++i) {
        int e = eord[s + i];
        int c = cols[e];
        float v = vals[e];
        acc = __fadd_rn(acc, __fmul_rn(v, x[(size_t)c * EMBD + lane]));
    }
    y[(size_t)r * EMBD + lane] = acc;
}

// ===========================================================================
// GAT, f32, XLA/Eigen-CPU flavored: FMA einsum chains, Eigen pexp softmax,
// tanh-form sigmoid, halving-tree reduces.
// ===========================================================================
__global__ __launch_bounds__(256) void gat_kernel(
        const float* __restrict__ item_emb,
        const float* __restrict__ ent_table,
        const float* __restrict__ fc_w,
        const float* __restrict__ fc_b,
        const float* __restrict__ rel_table,
        const int*   __restrict__ item_ents,
        const int*   __restrict__ item_rels,
        float*       __restrict__ nitems) {
    __shared__ float Wsh[128 * 64];        // fc_w, 32 KiB
    __shared__ float itemL[4][64];
    __shared__ float entL[4][64];
    __shared__ float red[4][64];

    int tid = threadIdx.x;
    for (int i = tid; i < 128 * 64; i += 256) Wsh[i] = fc_w[i];

    int w = tid >> 6, lane = tid & 63;
    int n = blockIdx.x * 4 + w;            // grid exact: 12500*4 = ITEMS
    float q = item_emb[(size_t)n * EMBD + lane];
    itemL[w][lane] = q;

    float ent[EPER], s16[EPER];

    for (int e = 0; e < EPER; ++e) {
        int eid = item_ents[n * EPER + e];
        int rid = item_rels[n * EPER + e];
        float ev = ent_table[(size_t)eid * EMBD + lane];
        ent[e] = ev;
        entL[w][lane] = ev;
        __syncthreads();
        // e_pre[d] = sum_{k} a_input[k]*fc_w[k][d] — sequential FMA chain (GEMM-like)
        float acc = 0.f;
        for (int k = 0; k < 64; ++k)
            acc = __fmaf_rn(itemL[w][k], Wsh[k * 64 + lane], acc);
        for (int k = 0; k < 64; ++k)
            acc = __fmaf_rn(entL[w][k], Wsh[(64 + k) * 64 + lane], acc);
        acc = __fadd_rn(acc, fc_b[lane]);                  // + fc_b
        float prod = __fmul_rn(acc, rel_table[rid * EMBD + lane]);  // * rel
        red[w][lane] = prod;
        __syncthreads();
        float esum = np_sum64(red[w], lane);               // halving tree
        float sc = (esum >= 0.f) ? esum : __fmul_rn(0.2f, esum);   // leaky_relu
        s16[e] = (eid != NENT) ? sc : -9.0e15f;            // mask
        __syncthreads();
    }

    // softmax over 16: Eigen pexp + halving-16 z-sum
    float m = s16[0];
    #pragma unroll
    for (int e = 1; e < EPER; ++e) m = fmaxf(m, s16[e]);
    float a16[EPER];
    #pragma unroll
    for (int e = 0; e < EPER; ++e) a16[e] = eigen_expf(__fsub_rn(s16[e], m));
    float s8[8];
    #pragma unroll
    for (int j = 0; j < 8; ++j) s8[j] = __fadd_rn(a16[j], a16[j + 8]);
    float t40 = __fadd_rn(s8[0], s8[4]);
    float t41 = __fadd_rn(s8[1], s8[5]);
    float t42 = __fadd_rn(s8[2], s8[6]);
    float t43 = __fadd_rn(s8[3], s8[7]);
    float z = __fadd_rn(__fadd_rn(t40, t42), __fadd_rn(t41, t43));

    // agg[d] = sum_e att[e]*ent[e][d] — sequential FMA chain over e
    float agg = 0.f;
    #pragma unroll
    for (int e = 0; e < EPER; ++e)
        agg = __fmaf_rn(__fdiv_rn(a16[e], z), ent[e], agg);

    float o = __fadd_rn(agg, q);                           // + item_embs
    // XLA logistic expansion: 0.5 + 0.5*tanh(0.5*x), Eigen ptanh
    float t = eigen_tanhf(__fmul_rn(0.5f, o));
    float sig = __fmaf_rn(0.5f, t, 0.5f);

    // l2 normalize (halving tree)
    __syncthreads();
    red[w][lane] = __fmul_rn(sig, sig);
    __syncthreads();
    float ss = np_sum64(red[w], lane);
    float nrm = fmaxf(__fsqrt_rn(ss), 1e-12f);
    nitems[(size_t)n * EMBD + lane] = __fdiv_rn(sig, nrm);
}

// ===========================================================================
// per-layer epilogue: ego = y + sign(y)*nn*0.1 ; output accumulation
// ===========================================================================
__global__ __launch_bounds__(256) void layer_kernel(
        float*       __restrict__ y,
        const float* __restrict__ noise_k,
        const float* __restrict__ nitems,
        float*       __restrict__ out,
        int k) {
    __shared__ float red[4][64];
    int tid = threadIdx.x, w = tid >> 6, lane = tid & 63;
    int n = blockIdx.x * 4 + w;            // grid exact: 37500*4 = NODES
    size_t idx = (size_t)n * EMBD + lane;

    float yv = y[idx];
    bool isu = (n < USERS);
    float v = isu ? noise_k[idx] : 0.f;
    red[w][lane] = __fmul_rn(v, v);
    __syncthreads();
    float ss = np_sum64(red[w], lane);

    float nn;
    if (isu) nn = __fdiv_rn(v, fmaxf(__fsqrt_rn(ss), 1e-12f));
    else     nn = nitems[(size_t)(n - USERS) * EMBD + lane];

    float sg  = (yv > 0.f) ? 1.f : ((yv < 0.f) ? -1.f : 0.f);
    float ego = __fadd_rn(yv, __fmul_rn(__fmul_rn(sg, nn), 0.1f));

    y[idx] = ego;

    const size_t CL_OFF = (size_t)NODES * EMBD;
    if (k == 0) {
        out[idx]          = ego;
        out[CL_OFF + idx] = ego;
    } else if (k == 1) {
        out[idx] = __fadd_rn(out[idx], ego);
    } else {
        out[idx] = __fdiv_rn(__fadd_rn(out[idx], ego), 3.0f);
    }
}

// ===========================================================================
extern "C" void kernel_launch(void* const* d_in, const int* in_sizes, int n_in,
                              void* d_out, int out_size, void* d_ws, size_t ws_size,
                              hipStream_t stream) {
    const float* user_emb   = (const float*)d_in[0];
    const float* item_emb   = (const float*)d_in[1];
    const float* ent_table  = (const float*)d_in[2];
    const float* rel_table  = (const float*)d_in[3];
    const float* fc_w       = (const float*)d_in[4];
    const float* fc_b       = (const float*)d_in[5];
    const int*   adj_rows   = (const int*)d_in[6];
    const int*   adj_cols   = (const int*)d_in[7];
    const float* adj_vals   = (const float*)d_in[8];
    const float* users_noise= (const float*)d_in[9];
    const int*   item_ents  = (const int*)d_in[10];
    const int*   item_rels  = (const int*)d_in[11];

    const size_t NE = (size_t)NODES * EMBD;        // 9.6M floats
    char* base = (char*)d_ws;
    size_t off = 0;
    float*  B0   = (float*)(base + off); off += NE * 4;
    float*  B1   = (float*)(base + off); off += NE * 4;
    float*  NIT  = (float*)(base + off); off += (size_t)ITEMS * EMBD * 4;
    int*    cnt  = (int*)(base + off);   off += 150016 * 4;
    int*    cur  = (int*)(base + off);   off += 150016 * 4;
    int*    rowp = (int*)(base + off);   off += 150016 * 4;
    int*    bsum = (int*)(base + off);   off += 1024 * 4;
    int*    eord = (int*)(base + off);   off += (size_t)NNZ_C * 4;
    float*  out  = (float*)d_out;

    // ---- stable CSR build (edge order within rows) ----
    hipMemsetAsync(cnt, 0, 150016 * 4, stream);
    hipMemsetAsync(cur, 0, 150016 * 4, stream);
    count_kernel<<<2048, 256, 0, stream>>>(adj_rows, cnt);
    scan1_kernel<<<NBLK_SCAN, 256, 0, stream>>>(cnt, bsum);
    scan2_kernel<<<1, 64, 0, stream>>>(bsum);
    scan3_kernel<<<NBLK_SCAN, 256, 0, stream>>>(cnt, bsum, rowp);
    scatter_kernel<<<2048, 256, 0, stream>>>(adj_rows, rowp, cur, eord);
    sortrow_kernel<<<(NODES + 255) / 256, 256, 0, stream>>>(rowp, cnt, eord);

    // ---- ego_0 = concat(user_emb, item_emb) ----
    hipMemcpyAsync(B0, user_emb, (size_t)USERS * EMBD * 4, hipMemcpyDeviceToDevice, stream);
    hipMemcpyAsync(B0 + (size_t)USERS * EMBD, item_emb, (size_t)ITEMS * EMBD * 4,
                   hipMemcpyDeviceToDevice, stream);

    gat_kernel<<<ITEMS / 4, 256, 0, stream>>>(item_emb, ent_table, fc_w, fc_b,
                                              rel_table, item_ents, item_rels, NIT);

    for (int k = 0; k < 3; ++k) {
        float* X = (k & 1) ? B1 : B0;
        float* Y = (k & 1) ? B0 : B1;
        spmm_seq_kernel<<<(NODES * 64 + 255) / 256, 256, 0, stream>>>(
            rowp, cnt, eord, adj_cols, adj_vals, X, Y);
        layer_kernel<<<NODES / 4, 256, 0, stream>>>(
            Y, users_noise + (size_t)k * USERS * EMBD, NIT, out, k);
    }
}

// Round 10
// 2274.044 us; speedup vs baseline: 1.5189x; 1.5189x over previous
//
#include <hip/hip_runtime.h>
#include <math.h>

#define EMBD   64
#define USERS  100000
#define ITEMS  50000
#define NODES  150000
#define NNZ_C  4500000
#define NENT   100000
#define EPER   16
#define NBLK_SCAN 586   // ceil(150000/256)

// ===========================================================================
// Eigen pexp_float replica (XLA:CPU vector exp) — EXACT copy of passing R9.
// ===========================================================================
__device__ __forceinline__ float eigen_expf(float x) {
    x = fminf(fmaxf(x, -87.33654785156250f), 88.72283935546875f);
    float m = floorf(__fmaf_rn(x, 1.44269504088896341f, 0.5f));
    float r = __fsub_rn(x, __fmul_rn(m, 0.693359375f));
    r = __fsub_rn(r, __fmul_rn(m, -2.12194440e-4f));
    float z = __fmul_rn(r, r);
    float y = 1.9875691500e-4f;
    y = __fmaf_rn(y, r, 1.3981999507e-3f);
    y = __fmaf_rn(y, r, 8.3334519073e-3f);
    y = __fmaf_rn(y, r, 4.1665795894e-2f);
    y = __fmaf_rn(y, r, 1.6666665459e-1f);
    y = __fmaf_rn(y, r, 5.0000001201e-1f);
    y = __fmaf_rn(y, z, r);
    y = __fadd_rn(y, 1.0f);
    int mi = (int)m;
    return __int_as_float(__float_as_int(y) + (mi << 23));
}

// ===========================================================================
// Eigen ptanh_float replica — EXACT copy of passing R9.
// ===========================================================================
__device__ __forceinline__ float eigen_tanhf(float x) {
    float ax = fabsf(x);
    float x2 = __fmul_rn(x, x);
    float p = -2.76076847742355e-16f;
    p = __fmaf_rn(p, x2, 2.00018790482477e-13f);
    p = __fmaf_rn(p, x2, -8.60467152213735e-11f);
    p = __fmaf_rn(p, x2, 5.12229709037114e-08f);
    p = __fmaf_rn(p, x2, 1.48572235717979e-05f);
    p = __fmaf_rn(p, x2, 6.37261928875436e-04f);
    p = __fmaf_rn(p, x2, 4.89352455891786e-03f);
    p = __fmul_rn(x, p);
    float q = 1.19825839466702e-06f;
    q = __fmaf_rn(q, x2, 1.18534705686654e-04f);
    q = __fmaf_rn(q, x2, 2.26843463243900e-03f);
    q = __fmaf_rn(q, x2, 4.89352518554385e-03f);
    float r = __fdiv_rn(p, q);
    return (ax < 4.0e-4f) ? x : r;
}

// ===========================================================================
// Register version of R9's np_sum64 — bitwise identical (IEEE add is
// commutative; pairings match (S[j]+S[j+16])+(S[j+32]+S[j+48]) then 8,4,2,1).
// ===========================================================================
__device__ __forceinline__ float wave_sum64(float x) {
    float v = __fadd_rn(x, __shfl_xor(x, 16));
    v = __fadd_rn(v, __shfl_xor(v, 32));
    v = __fadd_rn(v, __shfl_xor(v, 8));
    v = __fadd_rn(v, __shfl_xor(v, 4));
    v = __fadd_rn(v, __shfl_xor(v, 2));
    v = __fadd_rn(v, __shfl_xor(v, 1));
    return v;
}

// ===========================================================================
// CSR build: count -> scan -> stable scatter -> per-row sort by edge id
// ===========================================================================
__global__ void count_kernel(const int* __restrict__ rows, int* __restrict__ cnt) {
    int i = blockIdx.x * blockDim.x + threadIdx.x;
    int stride = gridDim.x * blockDim.x;
    for (; i < NNZ_C; i += stride) atomicAdd(&cnt[rows[i]], 1);
}

__global__ void scan1_kernel(const int* __restrict__ cnt, int* __restrict__ bsum) {
    __shared__ int s[256];
    int i = blockIdx.x * 256 + threadIdx.x;
    int v = (i < NODES) ? cnt[i] : 0;
    s[threadIdx.x] = v; __syncthreads();
    for (int o = 128; o; o >>= 1) {
        if (threadIdx.x < o) s[threadIdx.x] += s[threadIdx.x + o];
        __syncthreads();
    }
    if (threadIdx.x == 0) bsum[blockIdx.x] = s[0];
}

__global__ void scan2_kernel(int* __restrict__ bsum) {
    if (blockIdx.x == 0 && threadIdx.x == 0) {
        int acc = 0;
        for (int b = 0; b < NBLK_SCAN; ++b) { int t = bsum[b]; bsum[b] = acc; acc += t; }
    }
}

__global__ void scan3_kernel(const int* __restrict__ cnt, const int* __restrict__ bsum,
                             int* __restrict__ rowptr) {
    __shared__ int s[256];
    int tid = threadIdx.x;
    int i = blockIdx.x * 256 + tid;
    int v = (i < NODES) ? cnt[i] : 0;
    s[tid] = v; __syncthreads();
    for (int o = 1; o < 256; o <<= 1) {
        int t = (tid >= o) ? s[tid - o] : 0;
        __syncthreads();
        s[tid] += t;
        __syncthreads();
    }
    if (i < NODES) rowptr[i] = bsum[blockIdx.x] + s[tid] - v;   // exclusive
}

__global__ void scatter_kernel(const int* __restrict__ rows,
                               const int* __restrict__ rowptr,
                               int* __restrict__ cur, int* __restrict__ eord) {
    int i = blockIdx.x * blockDim.x + threadIdx.x;
    int stride = gridDim.x * blockDim.x;
    for (; i < NNZ_C; i += stride) {
        int r = rows[i];
        int slot = rowptr[r] + atomicAdd(&cur[r], 1);
        eord[slot] = i;
    }
}

__global__ void sortrow_kernel(const int* __restrict__ rowptr,
                               const int* __restrict__ cnt,
                               int* __restrict__ eord) {
    int r = blockIdx.x * blockDim.x + threadIdx.x;
    if (r >= NODES) return;
    int s = rowptr[r], n = cnt[r];
    for (int i = 1; i < n; ++i) {
        int key = eord[s + i];
        int j = i - 1;
        while (j >= 0 && eord[s + j] > key) { eord[s + j + 1] = eord[s + j]; --j; }
        eord[s + j + 1] = key;
    }
}

// gather cols/vals into slot order once (removes indirection in 3 spmm's)
__global__ void reorder_kernel(const int* __restrict__ eord,
                               const int* __restrict__ cols,
                               const float* __restrict__ vals,
                               int* __restrict__ cols2,
                               float* __restrict__ vals2) {
    int i = blockIdx.x * blockDim.x + threadIdx.x;
    int stride = gridDim.x * blockDim.x;
    for (; i < NNZ_C; i += stride) {
        int e = eord[i];
        cols2[i] = cols[e];
        vals2[i] = vals[e];
    }
}

// ===========================================================================
// SpMM: one wave per row, sequential f32 edge-order accumulation, NO FMA.
// Unroll-4 batches the gathers (MLP); add order strictly preserved.
// ===========================================================================
__global__ __launch_bounds__(256) void spmm_seq_kernel(
        const int*   __restrict__ rowptr,
        const int*   __restrict__ cnt,
        const int*   __restrict__ cols2,
        const float* __restrict__ vals2,
        const float* __restrict__ x,
        float*       __restrict__ y) {
    int lane = threadIdx.x & 63;
    int r = (blockIdx.x * blockDim.x + threadIdx.x) >> 6;
    if (r >= NODES) return;
    int s = rowptr[r], n = cnt[r];
    float acc = 0.f;
    int i = 0;
    for (; i + 4 <= n; i += 4) {
        int   c0 = cols2[s + i],     c1 = cols2[s + i + 1];
        int   c2 = cols2[s + i + 2], c3 = cols2[s + i + 3];
        float v0 = vals2[s + i],     v1 = vals2[s + i + 1];
        float v2 = vals2[s + i + 2], v3 = vals2[s + i + 3];
        float g0 = x[(size_t)c0 * EMBD + lane];
        float g1 = x[(size_t)c1 * EMBD + lane];
        float g2 = x[(size_t)c2 * EMBD + lane];
        float g3 = x[(size_t)c3 * EMBD + lane];
        acc = __fadd_rn(acc, __fmul_rn(v0, g0));
        acc = __fadd_rn(acc, __fmul_rn(v1, g1));
        acc = __fadd_rn(acc, __fmul_rn(v2, g2));
        acc = __fadd_rn(acc, __fmul_rn(v3, g3));
    }
    for (; i < n; ++i) {
        int   c = cols2[s + i];
        float v = vals2[s + i];
        acc = __fadd_rn(acc, __fmul_rn(v, x[(size_t)c * EMBD + lane]));
    }
    y[(size_t)r * EMBD + lane] = acc;
}

// ===========================================================================
// GAT — bitwise-identical arithmetic to R9, restructured for ILP:
//  * item-part prefix (first 64 k of the chain) computed ONCE, shared by 16
//    entity chains (identical op sequence -> identical bits).
//  * 16 entity chains run interleaved in registers (ILP=16), broadcast of
//    ent[e][k] via __shfl (pure data movement).
//  * all reductions are register shfl trees == R9's np_sum64 pairings.
//  * single __syncthreads (Wsh staging). 512-thread blocks, one wave/item.
// ===========================================================================
__global__ __launch_bounds__(512) void gat_kernel(
        const float* __restrict__ item_emb,
        const float* __restrict__ ent_table,
        const float* __restrict__ fc_w,
        const float* __restrict__ fc_b,
        const float* __restrict__ rel_table,
        const int*   __restrict__ item_ents,
        const int*   __restrict__ item_rels,
        float*       __restrict__ nitems) {
    __shared__ float Wsh[128 * 64];        // fc_w, 32 KiB
    int tid = threadIdx.x;
    for (int i = tid; i < 128 * 64; i += 512) Wsh[i] = fc_w[i];
    __syncthreads();

    int w = tid >> 6, lane = tid & 63;
    int n = blockIdx.x * 8 + w;            // grid exact: 6250*8 = ITEMS
    float q  = item_emb[(size_t)n * EMBD + lane];
    float bv = fc_b[lane];

    // ---- shared item-part prefix: acc over k=0..63 (sequential FMA chain)
    float accI = 0.f;
    for (int k = 0; k < 64; ++k)
        accI = __fmaf_rn(__shfl(q, k), Wsh[k * 64 + lane], accI);

    // ---- load the 16 entity rows (lane = d) ----
    float ev[EPER];
    int   eid[EPER];
    #pragma unroll
    for (int e = 0; e < EPER; ++e) {
        eid[e] = item_ents[n * EPER + e];
        ev[e]  = ent_table[(size_t)eid[e] * EMBD + lane];
    }

    // ---- 16 interleaved ent-part chains: k=64..127 continuation ----
    float acc[EPER];
    #pragma unroll
    for (int e = 0; e < EPER; ++e) acc[e] = accI;
    for (int k = 0; k < 64; ++k) {
        float wv = Wsh[(64 + k) * 64 + lane];
        #pragma unroll
        for (int e = 0; e < EPER; ++e)
            acc[e] = __fmaf_rn(__shfl(ev[e], k), wv, acc[e]);
    }

    // ---- finish per-entity score: +b, *rel, sum_d, leaky, mask ----
    float s16[EPER];
    #pragma unroll
    for (int e = 0; e < EPER; ++e) {
        int rid = item_rels[n * EPER + e];
        float pe   = __fadd_rn(acc[e], bv);
        float prod = __fmul_rn(pe, rel_table[rid * EMBD + lane]);
        float esum = wave_sum64(prod);
        float sc = (esum >= 0.f) ? esum : __fmul_rn(0.2f, esum);   // leaky_relu
        s16[e] = (eid[e] != NENT) ? sc : -9.0e15f;                 // mask
    }

    // ---- softmax over 16 (EXACT R9 op order) ----
    float m = s16[0];
    #pragma unroll
    for (int e = 1; e < EPER; ++e) m = fmaxf(m, s16[e]);
    float a16[EPER];
    #pragma unroll
    for (int e = 0; e < EPER; ++e) a16[e] = eigen_expf(__fsub_rn(s16[e], m));
    float s8[8];
    #pragma unroll
    for (int j = 0; j < 8; ++j) s8[j] = __fadd_rn(a16[j], a16[j + 8]);
    float t40 = __fadd_rn(s8[0], s8[4]);
    float t41 = __fadd_rn(s8[1], s8[5]);
    float t42 = __fadd_rn(s8[2], s8[6]);
    float t43 = __fadd_rn(s8[3], s8[7]);
    float z = __fadd_rn(__fadd_rn(t40, t42), __fadd_rn(t41, t43));

    // ---- agg: sequential FMA chain over e ----
    float agg = 0.f;
    #pragma unroll
    for (int e = 0; e < EPER; ++e)
        agg = __fmaf_rn(__fdiv_rn(a16[e], z), ev[e], agg);

    float o = __fadd_rn(agg, q);
    // XLA logistic: 0.5 + 0.5*tanh(0.5*x)
    float t = eigen_tanhf(__fmul_rn(0.5f, o));
    float sig = __fmaf_rn(0.5f, t, 0.5f);

    // ---- l2 normalize ----
    float ss = wave_sum64(__fmul_rn(sig, sig));
    float nrm = fmaxf(__fsqrt_rn(ss), 1e-12f);
    nitems[(size_t)n * EMBD + lane] = __fdiv_rn(sig, nrm);
}

// ===========================================================================
// per-layer epilogue: ego = y + sign(y)*nn*0.1 ; output accumulation
// (register shfl reduce — bitwise == R9's LDS np_sum64)
// ===========================================================================
__global__ __launch_bounds__(256) void layer_kernel(
        float*       __restrict__ y,
        const float* __restrict__ noise_k,
        const float* __restrict__ nitems,
        float*       __restrict__ out,
        int k) {
    int tid = threadIdx.x, w = tid >> 6, lane = tid & 63;
    int n = blockIdx.x * 4 + w;            // grid exact: 37500*4 = NODES
    size_t idx = (size_t)n * EMBD + lane;

    float yv = y[idx];
    bool isu = (n < USERS);
    float v = isu ? noise_k[idx] : 0.f;
    float ss = wave_sum64(__fmul_rn(v, v));

    float nn;
    if (isu) nn = __fdiv_rn(v, fmaxf(__fsqrt_rn(ss), 1e-12f));
    else     nn = nitems[(size_t)(n - USERS) * EMBD + lane];

    float sg  = (yv > 0.f) ? 1.f : ((yv < 0.f) ? -1.f : 0.f);
    float ego = __fadd_rn(yv, __fmul_rn(__fmul_rn(sg, nn), 0.1f));

    y[idx] = ego;

    const size_t CL_OFF = (size_t)NODES * EMBD;
    if (k == 0) {
        out[idx]          = ego;
        out[CL_OFF + idx] = ego;
    } else if (k == 1) {
        out[idx] = __fadd_rn(out[idx], ego);
    } else {
        out[idx] = __fdiv_rn(__fadd_rn(out[idx], ego), 3.0f);
    }
}

// ===========================================================================
extern "C" void kernel_launch(void* const* d_in, const int* in_sizes, int n_in,
                              void* d_out, int out_size, void* d_ws, size_t ws_size,
                              hipStream_t stream) {
    const float* user_emb   = (const float*)d_in[0];
    const float* item_emb   = (const float*)d_in[1];
    const float* ent_table  = (const float*)d_in[2];
    const float* rel_table  = (const float*)d_in[3];
    const float* fc_w       = (const float*)d_in[4];
    const float* fc_b       = (const float*)d_in[5];
    const int*   adj_rows   = (const int*)d_in[6];
    const int*   adj_cols   = (const int*)d_in[7];
    const float* adj_vals   = (const float*)d_in[8];
    const float* users_noise= (const float*)d_in[9];
    const int*   item_ents  = (const int*)d_in[10];
    const int*   item_rels  = (const int*)d_in[11];

    const size_t NE = (size_t)NODES * EMBD;        // 9.6M floats
    char* base = (char*)d_ws;
    size_t off = 0;
    float*  B0    = (float*)(base + off); off += NE * 4;
    float*  B1    = (float*)(base + off); off += NE * 4;
    float*  NIT   = (float*)(base + off); off += (size_t)ITEMS * EMBD * 4;
    int*    cnt   = (int*)(base + off);   off += 150016 * 4;
    int*    cur   = (int*)(base + off);   off += 150016 * 4;
    int*    rowp  = (int*)(base + off);   off += 150016 * 4;
    int*    bsum  = (int*)(base + off);   off += 1024 * 4;
    int*    eord  = (int*)(base + off);   off += (size_t)NNZ_C * 4;
    int*    cols2 = (int*)(base + off);   off += (size_t)NNZ_C * 4;
    float*  vals2 = (float*)(base + off); off += (size_t)NNZ_C * 4;
    float*  out   = (float*)d_out;

    // ---- stable CSR build (edge order within rows) ----
    hipMemsetAsync(cnt, 0, 150016 * 4, stream);
    hipMemsetAsync(cur, 0, 150016 * 4, stream);
    count_kernel<<<2048, 256, 0, stream>>>(adj_rows, cnt);
    scan1_kernel<<<NBLK_SCAN, 256, 0, stream>>>(cnt, bsum);
    scan2_kernel<<<1, 64, 0, stream>>>(bsum);
    scan3_kernel<<<NBLK_SCAN, 256, 0, stream>>>(cnt, bsum, rowp);
    scatter_kernel<<<2048, 256, 0, stream>>>(adj_rows, rowp, cur, eord);
    sortrow_kernel<<<(NODES + 255) / 256, 256, 0, stream>>>(rowp, cnt, eord);
    reorder_kernel<<<4096, 256, 0, stream>>>(eord, adj_cols, adj_vals, cols2, vals2);

    // ---- ego_0 = concat(user_emb, item_emb) ----
    hipMemcpyAsync(B0, user_emb, (size_t)USERS * EMBD * 4, hipMemcpyDeviceToDevice, stream);
    hipMemcpyAsync(B0 + (size_t)USERS * EMBD, item_emb, (size_t)ITEMS * EMBD * 4,
                   hipMemcpyDeviceToDevice, stream);

    gat_kernel<<<ITEMS / 8, 512, 0, stream>>>(item_emb, ent_table, fc_w, fc_b,
                                              rel_table, item_ents, item_rels, NIT);

    for (int k = 0; k < 3; ++k) {
        float* X = (k & 1) ? B1 : B0;
        float* Y = (k & 1) ? B0 : B1;
        spmm_seq_kernel<<<(NODES + 3) / 4, 256, 0, stream>>>(
            rowp, cnt, cols2, vals2, X, Y);
        layer_kernel<<<NODES / 4, 256, 0, stream>>>(
            Y, users_noise + (size_t)k * USERS * EMBD, NIT, out, k);
    }
}

// Round 11
// 1842.048 us; speedup vs baseline: 1.8751x; 1.2345x over previous
//
#include <hip/hip_runtime.h>
#include <math.h>

#define EMBD   64
#define USERS  100000
#define ITEMS  50000
#define NODES  150000
#define NNZ_C  4500000
#define NENT   100000
#define EPER   16
#define NBLK_SCAN 586   // ceil(150000/256)

// ===========================================================================
// Eigen pexp_float replica (XLA:CPU vector exp) — EXACT copy of passing R9.
// ===========================================================================
__device__ __forceinline__ float eigen_expf(float x) {
    x = fminf(fmaxf(x, -87.33654785156250f), 88.72283935546875f);
    float m = floorf(__fmaf_rn(x, 1.44269504088896341f, 0.5f));
    float r = __fsub_rn(x, __fmul_rn(m, 0.693359375f));
    r = __fsub_rn(r, __fmul_rn(m, -2.12194440e-4f));
    float z = __fmul_rn(r, r);
    float y = 1.9875691500e-4f;
    y = __fmaf_rn(y, r, 1.3981999507e-3f);
    y = __fmaf_rn(y, r, 8.3334519073e-3f);
    y = __fmaf_rn(y, r, 4.1665795894e-2f);
    y = __fmaf_rn(y, r, 1.6666665459e-1f);
    y = __fmaf_rn(y, r, 5.0000001201e-1f);
    y = __fmaf_rn(y, z, r);
    y = __fadd_rn(y, 1.0f);
    int mi = (int)m;
    return __int_as_float(__float_as_int(y) + (mi << 23));
}

// ===========================================================================
// Eigen ptanh_float replica — EXACT copy of passing R9.
// ===========================================================================
__device__ __forceinline__ float eigen_tanhf(float x) {
    float ax = fabsf(x);
    float x2 = __fmul_rn(x, x);
    float p = -2.76076847742355e-16f;
    p = __fmaf_rn(p, x2, 2.00018790482477e-13f);
    p = __fmaf_rn(p, x2, -8.60467152213735e-11f);
    p = __fmaf_rn(p, x2, 5.12229709037114e-08f);
    p = __fmaf_rn(p, x2, 1.48572235717979e-05f);
    p = __fmaf_rn(p, x2, 6.37261928875436e-04f);
    p = __fmaf_rn(p, x2, 4.89352455891786e-03f);
    p = __fmul_rn(x, p);
    float q = 1.19825839466702e-06f;
    q = __fmaf_rn(q, x2, 1.18534705686654e-04f);
    q = __fmaf_rn(q, x2, 2.26843463243900e-03f);
    q = __fmaf_rn(q, x2, 4.89352518554385e-03f);
    float r = __fdiv_rn(p, q);
    return (ax < 4.0e-4f) ? x : r;
}

// ===========================================================================
// wave_sum64 — bitwise identical to R9's np_sum64 (commutative-add pairings).
// ===========================================================================
__device__ __forceinline__ float wave_sum64(float x) {
    float v = __fadd_rn(x, __shfl_xor(x, 16));
    v = __fadd_rn(v, __shfl_xor(v, 32));
    v = __fadd_rn(v, __shfl_xor(v, 8));
    v = __fadd_rn(v, __shfl_xor(v, 4));
    v = __fadd_rn(v, __shfl_xor(v, 2));
    v = __fadd_rn(v, __shfl_xor(v, 1));
    return v;
}

// exact wave-uniform broadcast via VALU readlane (no DS pipe)
__device__ __forceinline__ float rdlane(float v, int l) {
    return __int_as_float(__builtin_amdgcn_readlane(__float_as_int(v), l));
}

// ===========================================================================
// CSR build: count -> scan -> stable scatter -> per-row sort by edge id
// ===========================================================================
__global__ void count_kernel(const int* __restrict__ rows, int* __restrict__ cnt) {
    int i = blockIdx.x * blockDim.x + threadIdx.x;
    int stride = gridDim.x * blockDim.x;
    for (; i < NNZ_C; i += stride) atomicAdd(&cnt[rows[i]], 1);
}

__global__ void scan1_kernel(const int* __restrict__ cnt, int* __restrict__ bsum) {
    __shared__ int s[256];
    int i = blockIdx.x * 256 + threadIdx.x;
    int v = (i < NODES) ? cnt[i] : 0;
    s[threadIdx.x] = v; __syncthreads();
    for (int o = 128; o; o >>= 1) {
        if (threadIdx.x < o) s[threadIdx.x] += s[threadIdx.x + o];
        __syncthreads();
    }
    if (threadIdx.x == 0) bsum[blockIdx.x] = s[0];
}

__global__ void scan2_kernel(int* __restrict__ bsum) {
    if (blockIdx.x == 0 && threadIdx.x == 0) {
        int acc = 0;
        for (int b = 0; b < NBLK_SCAN; ++b) { int t = bsum[b]; bsum[b] = acc; acc += t; }
    }
}

__global__ void scan3_kernel(const int* __restrict__ cnt, const int* __restrict__ bsum,
                             int* __restrict__ rowptr) {
    __shared__ int s[256];
    int tid = threadIdx.x;
    int i = blockIdx.x * 256 + tid;
    int v = (i < NODES) ? cnt[i] : 0;
    s[tid] = v; __syncthreads();
    for (int o = 1; o < 256; o <<= 1) {
        int t = (tid >= o) ? s[tid - o] : 0;
        __syncthreads();
        s[tid] += t;
        __syncthreads();
    }
    if (i < NODES) rowptr[i] = bsum[blockIdx.x] + s[tid] - v;   // exclusive
}

__global__ void scatter_kernel(const int* __restrict__ rows,
                               const int* __restrict__ rowptr,
                               int* __restrict__ cur, int* __restrict__ eord) {
    int i = blockIdx.x * blockDim.x + threadIdx.x;
    int stride = gridDim.x * blockDim.x;
    for (; i < NNZ_C; i += stride) {
        int r = rows[i];
        int slot = rowptr[r] + atomicAdd(&cur[r], 1);
        eord[slot] = i;
    }
}

__global__ void sortrow_kernel(const int* __restrict__ rowptr,
                               const int* __restrict__ cnt,
                               int* __restrict__ eord) {
    int r = blockIdx.x * blockDim.x + threadIdx.x;
    if (r >= NODES) return;
    int s = rowptr[r], n = cnt[r];
    for (int i = 1; i < n; ++i) {
        int key = eord[s + i];
        int j = i - 1;
        while (j >= 0 && eord[s + j] > key) { eord[s + j + 1] = eord[s + j]; --j; }
        eord[s + j + 1] = key;
    }
}

// gather cols/vals into slot order once
__global__ void reorder_kernel(const int* __restrict__ eord,
                               const int* __restrict__ cols,
                               const float* __restrict__ vals,
                               int* __restrict__ cols2,
                               float* __restrict__ vals2) {
    int i = blockIdx.x * blockDim.x + threadIdx.x;
    int stride = gridDim.x * blockDim.x;
    for (; i < NNZ_C; i += stride) {
        int e = eord[i];
        cols2[i] = cols[e];
        vals2[i] = vals[e];
    }
}

// ===========================================================================
// Fused SpMM + layer epilogue. One wave per row.
// SpMM: sequential f32 edge-order accumulation, NO FMA, double-buffered
// batch-8 prefetch (gathers for batch i+1 issue before batch i's add chain).
// Then: ego = y + sign(y)*nn*0.1 ; write Y and out (same op order as R9/R10).
// ===========================================================================
#define NB 8
__global__ __launch_bounds__(256) void spmm_layer_kernel(
        const int*   __restrict__ rowptr,
        const int*   __restrict__ cnt,
        const int*   __restrict__ cols2,
        const float* __restrict__ vals2,
        const float* __restrict__ x,
        float*       __restrict__ y,
        const float* __restrict__ noise_k,
        const float* __restrict__ nitems,
        float*       __restrict__ out,
        int k) {
    int lane = threadIdx.x & 63;
    int r = (blockIdx.x * blockDim.x + threadIdx.x) >> 6;
    if (r >= NODES) return;
    int s = rowptr[r], n = cnt[r];

    float acc = 0.f;
    int i = 0;
    if (n >= NB) {
        float v[NB], g[NB];
        #pragma unroll
        for (int j = 0; j < NB; ++j) {
            int c = cols2[s + j];
            v[j] = vals2[s + j];
            g[j] = x[(size_t)c * EMBD + lane];
        }
        for (i = NB; i + NB <= n; i += NB) {
            float v2[NB], g2[NB];
            #pragma unroll
            for (int j = 0; j < NB; ++j) {
                int c = cols2[s + i + j];
                v2[j] = vals2[s + i + j];
                g2[j] = x[(size_t)c * EMBD + lane];
            }
            #pragma unroll
            for (int j = 0; j < NB; ++j)
                acc = __fadd_rn(acc, __fmul_rn(v[j], g[j]));
            #pragma unroll
            for (int j = 0; j < NB; ++j) { v[j] = v2[j]; g[j] = g2[j]; }
        }
        #pragma unroll
        for (int j = 0; j < NB; ++j)
            acc = __fadd_rn(acc, __fmul_rn(v[j], g[j]));
    }
    for (; i < n; ++i) {
        int   c = cols2[s + i];
        float v = vals2[s + i];
        acc = __fadd_rn(acc, __fmul_rn(v, x[(size_t)c * EMBD + lane]));
    }

    // ---- layer epilogue (identical op order to R10's layer_kernel) ----
    size_t idx = (size_t)r * EMBD + lane;
    float yv = acc;
    bool isu = (r < USERS);
    float v = isu ? noise_k[idx] : 0.f;
    float ss = wave_sum64(__fmul_rn(v, v));

    float nn;
    if (isu) nn = __fdiv_rn(v, fmaxf(__fsqrt_rn(ss), 1e-12f));
    else     nn = nitems[(size_t)(r - USERS) * EMBD + lane];

    float sg  = (yv > 0.f) ? 1.f : ((yv < 0.f) ? -1.f : 0.f);
    float ego = __fadd_rn(yv, __fmul_rn(__fmul_rn(sg, nn), 0.1f));

    y[idx] = ego;

    const size_t CL_OFF = (size_t)NODES * EMBD;
    if (k == 0) {
        out[idx]          = ego;
        out[CL_OFF + idx] = ego;
    } else if (k == 1) {
        out[idx] = __fadd_rn(out[idx], ego);
    } else {
        out[idx] = __fdiv_rn(__fadd_rn(out[idx], ego), 3.0f);
    }
}

// ===========================================================================
// GAT — bitwise-identical arithmetic to R9/R10; broadcasts via v_readlane
// (VALU) instead of __shfl (DS pipe). Single barrier (Wsh staging).
// ===========================================================================
__global__ __launch_bounds__(512) void gat_kernel(
        const float* __restrict__ item_emb,
        const float* __restrict__ ent_table,
        const float* __restrict__ fc_w,
        const float* __restrict__ fc_b,
        const float* __restrict__ rel_table,
        const int*   __restrict__ item_ents,
        const int*   __restrict__ item_rels,
        float*       __restrict__ nitems) {
    __shared__ float Wsh[128 * 64];        // fc_w, 32 KiB
    int tid = threadIdx.x;
    for (int i = tid; i < 128 * 64; i += 512) Wsh[i] = fc_w[i];
    __syncthreads();

    int w = tid >> 6, lane = tid & 63;
    int n = blockIdx.x * 8 + w;            // grid exact: 6250*8 = ITEMS
    float q  = item_emb[(size_t)n * EMBD + lane];
    float bv = fc_b[lane];

    // ---- shared item-part prefix: k=0..63 sequential FMA chain ----
    float accI = 0.f;
    #pragma unroll 8
    for (int k = 0; k < 64; ++k)
        accI = __fmaf_rn(rdlane(q, k), Wsh[k * 64 + lane], accI);

    // ---- load the 16 entity rows (lane = d) ----
    float ev[EPER];
    int   eid[EPER];
    #pragma unroll
    for (int e = 0; e < EPER; ++e) {
        eid[e] = item_ents[n * EPER + e];
        ev[e]  = ent_table[(size_t)eid[e] * EMBD + lane];
    }

    // ---- 16 interleaved ent-part chains: k=64..127 continuation ----
    float acc[EPER];
    #pragma unroll
    for (int e = 0; e < EPER; ++e) acc[e] = accI;
    #pragma unroll 4
    for (int k = 0; k < 64; ++k) {
        float wv = Wsh[(64 + k) * 64 + lane];
        #pragma unroll
        for (int e = 0; e < EPER; ++e)
            acc[e] = __fmaf_rn(rdlane(ev[e], k), wv, acc[e]);
    }

    // ---- finish per-entity score: +b, *rel, sum_d, leaky, mask ----
    float s16[EPER];
    #pragma unroll
    for (int e = 0; e < EPER; ++e) {
        int rid = item_rels[n * EPER + e];
        float pe   = __fadd_rn(acc[e], bv);
        float prod = __fmul_rn(pe, rel_table[rid * EMBD + lane]);
        float esum = wave_sum64(prod);
        float sc = (esum >= 0.f) ? esum : __fmul_rn(0.2f, esum);   // leaky_relu
        s16[e] = (eid[e] != NENT) ? sc : -9.0e15f;                 // mask
    }

    // ---- softmax over 16 (EXACT R9 op order) ----
    float m = s16[0];
    #pragma unroll
    for (int e = 1; e < EPER; ++e) m = fmaxf(m, s16[e]);
    float a16[EPER];
    #pragma unroll
    for (int e = 0; e < EPER; ++e) a16[e] = eigen_expf(__fsub_rn(s16[e], m));
    float s8[8];
    #pragma unroll
    for (int j = 0; j < 8; ++j) s8[j] = __fadd_rn(a16[j], a16[j + 8]);
    float t40 = __fadd_rn(s8[0], s8[4]);
    float t41 = __fadd_rn(s8[1], s8[5]);
    float t42 = __fadd_rn(s8[2], s8[6]);
    float t43 = __fadd_rn(s8[3], s8[7]);
    float z = __fadd_rn(__fadd_rn(t40, t42), __fadd_rn(t41, t43));

    // ---- agg: sequential FMA chain over e ----
    float agg = 0.f;
    #pragma unroll
    for (int e = 0; e < EPER; ++e)
        agg = __fmaf_rn(__fdiv_rn(a16[e], z), ev[e], agg);

    float o = __fadd_rn(agg, q);
    float t = eigen_tanhf(__fmul_rn(0.5f, o));     // XLA logistic
    float sig = __fmaf_rn(0.5f, t, 0.5f);

    float ss = wave_sum64(__fmul_rn(sig, sig));
    float nrm = fmaxf(__fsqrt_rn(ss), 1e-12f);
    nitems[(size_t)n * EMBD + lane] = __fdiv_rn(sig, nrm);
}

// ===========================================================================
extern "C" void kernel_launch(void* const* d_in, const int* in_sizes, int n_in,
                              void* d_out, int out_size, void* d_ws, size_t ws_size,
                              hipStream_t stream) {
    const float* user_emb   = (const float*)d_in[0];
    const float* item_emb   = (const float*)d_in[1];
    const float* ent_table  = (const float*)d_in[2];
    const float* rel_table  = (const float*)d_in[3];
    const float* fc_w       = (const float*)d_in[4];
    const float* fc_b       = (const float*)d_in[5];
    const int*   adj_rows   = (const int*)d_in[6];
    const int*   adj_cols   = (const int*)d_in[7];
    const float* adj_vals   = (const float*)d_in[8];
    const float* users_noise= (const float*)d_in[9];
    const int*   item_ents  = (const int*)d_in[10];
    const int*   item_rels  = (const int*)d_in[11];

    const size_t NE = (size_t)NODES * EMBD;        // 9.6M floats
    char* base = (char*)d_ws;
    size_t off = 0;
    float*  B0    = (float*)(base + off); off += NE * 4;
    float*  B1    = (float*)(base + off); off += NE * 4;
    float*  NIT   = (float*)(base + off); off += (size_t)ITEMS * EMBD * 4;
    int*    cnt   = (int*)(base + off);   off += 150016 * 4;
    int*    cur   = (int*)(base + off);   off += 150016 * 4;
    int*    rowp  = (int*)(base + off);   off += 150016 * 4;
    int*    bsum  = (int*)(base + off);   off += 1024 * 4;
    int*    eord  = (int*)(base + off);   off += (size_t)NNZ_C * 4;
    int*    cols2 = (int*)(base + off);   off += (size_t)NNZ_C * 4;
    float*  vals2 = (float*)(base + off); off += (size_t)NNZ_C * 4;
    float*  out   = (float*)d_out;

    // ---- stable CSR build (edge order within rows) ----
    hipMemsetAsync(cnt, 0, 150016 * 4, stream);
    hipMemsetAsync(cur, 0, 150016 * 4, stream);
    count_kernel<<<2048, 256, 0, stream>>>(adj_rows, cnt);
    scan1_kernel<<<NBLK_SCAN, 256, 0, stream>>>(cnt, bsum);
    scan2_kernel<<<1, 64, 0, stream>>>(bsum);
    scan3_kernel<<<NBLK_SCAN, 256, 0, stream>>>(cnt, bsum, rowp);
    scatter_kernel<<<2048, 256, 0, stream>>>(adj_rows, rowp, cur, eord);
    sortrow_kernel<<<(NODES + 255) / 256, 256, 0, stream>>>(rowp, cnt, eord);
    reorder_kernel<<<4096, 256, 0, stream>>>(eord, adj_cols, adj_vals, cols2, vals2);

    // ---- ego_0 = concat(user_emb, item_emb) ----
    hipMemcpyAsync(B0, user_emb, (size_t)USERS * EMBD * 4, hipMemcpyDeviceToDevice, stream);
    hipMemcpyAsync(B0 + (size_t)USERS * EMBD, item_emb, (size_t)ITEMS * EMBD * 4,
                   hipMemcpyDeviceToDevice, stream);

    gat_kernel<<<ITEMS / 8, 512, 0, stream>>>(item_emb, ent_table, fc_w, fc_b,
                                              rel_table, item_ents, item_rels, NIT);

    for (int k = 0; k < 3; ++k) {
        float* X = (k & 1) ? B1 : B0;
        float* Y = (k & 1) ? B0 : B1;
        spmm_layer_kernel<<<(NODES + 3) / 4, 256, 0, stream>>>(
            rowp, cnt, cols2, vals2, X, Y,
            users_noise + (size_t)k * USERS * EMBD, NIT, out, k);
    }
}